// Round 15
// baseline (280.253 us; speedup 1.0000x reference)
//
#include <hip/hip_runtime.h>
#include <stdint.h>

// FactoredAttention: x[16384,1024] f32 -> (x->bf16) -> qkv GEMM -> 16-block
// causal attn -> proj GEMM -> out f32.  I/O f32; bf16 compute/intermediates.
// ws: qkv bf16 (16384*3072) | w_attnT bf16 (3072*1024) | w_projT bf16 (1024*1024)
// xbf16 (33.5MB) lives in d_out scratch (dead before GEMM2 writes it).
// R15: GEMMs reverted to R12 (best total, 245.8).  Attn: merged-quarter
// blocks — each (nb,h,pair) block sweeps tiles ONCE, processing both of its
// quarters per tile (A if active, then B).  Stage-iters 20 -> 14 per (nb,h),
// syncthreads likewise; MFMA/softmax work unchanged (skipped tiles provably
// fully-masked).

typedef __bf16 bf16x8 __attribute__((ext_vector_type(8)));
typedef short short8 __attribute__((ext_vector_type(8)));
typedef float f32x4 __attribute__((ext_vector_type(4)));
typedef unsigned short ushort4v __attribute__((ext_vector_type(4)));
typedef unsigned short ushort8v __attribute__((ext_vector_type(8)));

#define GLOAD_LDS16(g, l)                                                      \
  __builtin_amdgcn_global_load_lds(                                            \
      (const __attribute__((address_space(1))) void*)(g),                      \
      (__attribute__((address_space(3))) void*)(l), 16, 0, 0)

static __device__ __forceinline__ f32x4 mfma16(short8 a, short8 b, f32x4 c) {
  return __builtin_amdgcn_mfma_f32_16x16x32_bf16(
      __builtin_bit_cast(bf16x8, a), __builtin_bit_cast(bf16x8, b), c, 0, 0, 0);
}

static __device__ __forceinline__ unsigned short f2bf(float f) {
  unsigned u = __builtin_bit_cast(unsigned, f);
  u += 0x7FFFu + ((u >> 16) & 1u);
  return (unsigned short)(u >> 16);
}

// ---------------------------------------------------------------------------
// f32 -> bf16 elementwise convert (vectorized, grid-stride).
// ---------------------------------------------------------------------------
__global__ __launch_bounds__(256) void convert_bf16(
    const float* __restrict__ in, unsigned short* __restrict__ out, int n8) {
  for (int i = blockIdx.x * 256 + threadIdx.x; i < n8; i += gridDim.x * 256) {
    f32x4 lo = *(const f32x4*)(in + (size_t)i * 8);
    f32x4 hi = *(const f32x4*)(in + (size_t)i * 8 + 4);
    ushort8v v;
    v[0] = f2bf(lo[0]); v[1] = f2bf(lo[1]); v[2] = f2bf(lo[2]); v[3] = f2bf(lo[3]);
    v[4] = f2bf(hi[0]); v[5] = f2bf(hi[1]); v[6] = f2bf(hi[2]); v[7] = f2bf(hi[3]);
    *(ushort8v*)(out + (size_t)i * 8) = v;
  }
}

// ---------------------------------------------------------------------------
// Transpose + convert: in f32 [K][N] -> out bf16 [N][K].  grid (N/64, K/64).
// ---------------------------------------------------------------------------
__global__ __launch_bounds__(256) void transposeW(
    const float* __restrict__ in, unsigned short* __restrict__ out,
    int K, int N) {
  __shared__ float tile[64][68];
  int tn = blockIdx.x * 64, tk = blockIdx.y * 64;
  int tid = threadIdx.x;
#pragma unroll
  for (int i = 0; i < 4; ++i) {
    int ch = i * 256 + tid;
    int r = ch >> 4, c4 = (ch & 15) << 2;
    f32x4 v = *(const f32x4*)(in + (size_t)(tk + r) * N + tn + c4);
    tile[r][c4] = v[0]; tile[r][c4 + 1] = v[1];
    tile[r][c4 + 2] = v[2]; tile[r][c4 + 3] = v[3];
  }
  __syncthreads();
#pragma unroll
  for (int i = 0; i < 4; ++i) {
    int ch = i * 256 + tid;
    int r = ch >> 4, c4 = (ch & 15) << 2;
    ushort4v v;
    v[0] = f2bf(tile[c4][r]);     v[1] = f2bf(tile[c4 + 1][r]);
    v[2] = f2bf(tile[c4 + 2][r]); v[3] = f2bf(tile[c4 + 3][r]);
    *(ushort4v*)(out + (size_t)(tn + r) * K + tk + c4) = v;
  }
}

// ---------------------------------------------------------------------------
// C[M][N] = A[M][K] * Bt[N][K]^T + bias(f32).  A,Bt bf16.  (R12 verbatim)
// 256x256 tile, BK=64, 512 threads (2M x 4N waves, 128x64 out each).
// LDS double-buffer (128KB).  Per K-tile: vmcnt(0) handoff (all outstanding =
// this tile's stages, issued during the previous tile's phases), then 4
// quadrant phases, each:
//   {ds_read A-quad 4xb128 [+B 8xb128 in phase0]; 2x global_load_lds for
//    next tile's quarter q; [phase0: lgkmcnt(8)]; s_barrier; lgkmcnt(0)+
//    sched_barrier; setprio(1); 16 MFMA; setprio(0); s_barrier}
// Swizzle byte ^= (row&7)<<4 with inverse-swizzled global source (0-conflict).
// grid.x % 8 == 0 (XCD swizzle).
// ---------------------------------------------------------------------------
template <bool C_F32>
__global__ __launch_bounds__(512, 2) void gemm256(
    const unsigned short* __restrict__ A, int lda,
    const unsigned short* __restrict__ Bt, int ldb,
    const float* __restrict__ bias,
    void* __restrict__ Cptr, int ldc,
    int Ntiles, int K) {
  __shared__ unsigned short sA[2][256 * 64];
  __shared__ unsigned short sB[2][256 * 64];
  int bid = blockIdx.x;
  int nwg = gridDim.x;
  int swz = (bid & 7) * (nwg >> 3) + (bid >> 3);
  int bm = swz / Ntiles, bn = swz % Ntiles;
  int tid = threadIdx.x;
  int lane = tid & 63, wave = tid >> 6;
  int wr = wave >> 2, wc = wave & 3;  // 2M x 4N wave grid
  int g = lane >> 4, cx = lane & 15;

  const unsigned short* srcA[4];
  const unsigned short* srcB[4];
  int dstoff[4];
#pragma unroll
  for (int i = 0; i < 4; ++i) {
    int c = i * 512 + tid;
    int r = c >> 3, pc = c & 7;
    int cc = pc ^ (r & 7);  // inverse-swizzled source chunk
    srcA[i] = A + (size_t)(bm * 256 + r) * lda + cc * 8;
    srcB[i] = Bt + (size_t)(bn * 256 + r) * ldb + cc * 8;
    dstoff[i] = (i * 512 + wave * 64) * 8;
  }

  f32x4 zero4 = {0.f, 0.f, 0.f, 0.f};
  f32x4 acc[8][4];
#pragma unroll
  for (int a = 0; a < 8; ++a)
#pragma unroll
    for (int b = 0; b < 4; ++b) acc[a][b] = zero4;

  int NT = K >> 6;

  // prologue: stage tile 0 into buffer 0 in consumption order
  GLOAD_LDS16(srcB[0], sB[0] + dstoff[0]);
  GLOAD_LDS16(srcB[1], sB[0] + dstoff[1]);
  GLOAD_LDS16(srcB[2], sB[0] + dstoff[2]);
  GLOAD_LDS16(srcB[3], sB[0] + dstoff[3]);
  GLOAD_LDS16(srcA[0], sA[0] + dstoff[0]);
  GLOAD_LDS16(srcA[2], sA[0] + dstoff[2]);
  GLOAD_LDS16(srcA[1], sA[0] + dstoff[1]);
  GLOAD_LDS16(srcA[3], sA[0] + dstoff[3]);

  for (int t = 0; t < NT; ++t) {
    int p = t & 1;
    // tile-top handoff: all outstanding VMEM = this tile's stages
    asm volatile("s_waitcnt vmcnt(0)" ::: "memory");
    __builtin_amdgcn_sched_barrier(0);
    __builtin_amdgcn_s_barrier();
    __builtin_amdgcn_sched_barrier(0);

    const char* bA = (const char*)sA[p];
    const char* bB = (const char*)sB[p];
    unsigned short* nA = sA[p ^ 1];
    unsigned short* nB = sB[p ^ 1];
    bool pre = (t + 1 < NT);
    int kt = (t + 1) * 64;
    short8 bfr[4][2];

#define READ_A(afv, q)                                                         \
  _Pragma("unroll") for (int mm = 0; mm < 2; ++mm)                             \
      _Pragma("unroll") for (int ks = 0; ks < 2; ++ks) {                       \
    int row = wr * 128 + ((q) * 2 + mm) * 16 + cx;                             \
    unsigned off = (unsigned)(row * 128 + ks * 64 + g * 16) ^                  \
                   ((unsigned)(row & 7) << 4);                                 \
    afv[mm][ks] = *(const short8*)(bA + off);                                  \
  }
#define MFMA_Q(afv, q)                                                         \
  __builtin_amdgcn_s_setprio(1);                                               \
  _Pragma("unroll") for (int mm = 0; mm < 2; ++mm)                             \
      _Pragma("unroll") for (int ni = 0; ni < 4; ++ni)                         \
          _Pragma("unroll") for (int ks = 0; ks < 2; ++ks)                     \
      acc[(q) * 2 + mm][ni] =                                                  \
          mfma16(afv[mm][ks], bfr[ni][ks], acc[(q) * 2 + mm][ni]);             \
  __builtin_amdgcn_s_setprio(0);
#define PHASE_TAIL()                                                           \
  __builtin_amdgcn_sched_barrier(0);                                           \
  __builtin_amdgcn_s_barrier();                                                \
  asm volatile("s_waitcnt lgkmcnt(0)" ::: "memory");                           \
  __builtin_amdgcn_sched_barrier(0);
#define PHASE_END()                                                            \
  __builtin_amdgcn_sched_barrier(0);                                           \
  __builtin_amdgcn_s_barrier();                                                \
  __builtin_amdgcn_sched_barrier(0);

    // ---- phase 0: B full + A quad0; stage B0',B1' ----
    {
#pragma unroll
      for (int ni = 0; ni < 4; ++ni)
#pragma unroll
        for (int ks = 0; ks < 2; ++ks) {
          int row = wc * 64 + ni * 16 + cx;
          unsigned off = (unsigned)(row * 128 + ks * 64 + g * 16) ^
                         ((unsigned)(row & 7) << 4);
          bfr[ni][ks] = *(const short8*)(bB + off);
        }
      short8 af[2][2];
      READ_A(af, 0);
      if (pre) {
        GLOAD_LDS16(srcB[0] + kt, nB + dstoff[0]);
        GLOAD_LDS16(srcB[1] + kt, nB + dstoff[1]);
      }
      asm volatile("s_waitcnt lgkmcnt(8)" ::: "memory");
      PHASE_TAIL();
      MFMA_Q(af, 0);
      PHASE_END();
    }
    // ---- phase 1: A quad1; stage B2',B3' ----
    {
      short8 af[2][2];
      READ_A(af, 1);
      if (pre) {
        GLOAD_LDS16(srcB[2] + kt, nB + dstoff[2]);
        GLOAD_LDS16(srcB[3] + kt, nB + dstoff[3]);
      }
      PHASE_TAIL();
      MFMA_Q(af, 1);
      PHASE_END();
    }
    // ---- phase 2: A quad2; stage A0',A2' ----
    {
      short8 af[2][2];
      READ_A(af, 2);
      if (pre) {
        GLOAD_LDS16(srcA[0] + kt, nA + dstoff[0]);
        GLOAD_LDS16(srcA[2] + kt, nA + dstoff[2]);
      }
      PHASE_TAIL();
      MFMA_Q(af, 2);
      PHASE_END();
    }
    // ---- phase 3: A quad3; stage A1',A3' ----
    {
      short8 af[2][2];
      READ_A(af, 3);
      if (pre) {
        GLOAD_LDS16(srcA[1] + kt, nA + dstoff[1]);
        GLOAD_LDS16(srcA[3] + kt, nA + dstoff[3]);
      }
      PHASE_TAIL();
      MFMA_Q(af, 3);
      PHASE_END();
    }
#undef READ_A
#undef MFMA_Q
#undef PHASE_TAIL
#undef PHASE_END
  }

  float bv[4];
#pragma unroll
  for (int ni = 0; ni < 4; ++ni)
    bv[ni] = bias[bn * 256 + wc * 64 + ni * 16 + cx];

#pragma unroll
  for (int mi = 0; mi < 8; ++mi)
#pragma unroll
    for (int ni = 0; ni < 4; ++ni) {
      int col = bn * 256 + wc * 64 + ni * 16 + cx;
#pragma unroll
      for (int ri = 0; ri < 4; ++ri) {
        int row = bm * 256 + wr * 128 + mi * 16 + g * 4 + ri;
        float v = acc[mi][ni][ri] + bv[ni];
        if (C_F32)
          ((float*)Cptr)[(size_t)row * ldc + col] = v;
        else
          ((unsigned short*)Cptr)[(size_t)row * ldc + col] = f2bf(v);
      }
    }
}

// ---------------------------------------------------------------------------
// Block-causal flash attention, in-place (O overwrites q slice of qkv).
// grid: 32 nb * 16 h * 2 pairs = 1024 blocks, 4 waves.
// R15: merged quarters — block (nb,h,pair) owns quarters {qa,qb} =
// {0,3} (pair 0) or {1,2} (pair 1); ONE tile sweep t=0..2*qb+1, staging K/V
// once per tile and processing quarter A (while active: t <= 2*qa+1) then
// quarter B.  Skipped (A-inactive) tiles are fully masked for A -> exact.
// Frags f: 0,1 -> quarter qa ni=0,1; 2,3 -> quarter qb ni=0,1.
// S^T = mfma(K, Q) -> softmax lane-local at q = lane&15; O^T = mfma(V^T, P^T).
// sVT swizzle: byte = (d*128 + 2k) ^ (((d>>3)^d)&7)<<4 (conflict-free both
// sides); K/P swizzle byte ^= (row&7)<<4.  LDS 32KB -> 5 blocks/CU.
// Per-wave P buffer reused A-then-B (in-wave DS ordering).
// ---------------------------------------------------------------------------
__global__ __launch_bounds__(256) void attn_block(unsigned short* __restrict__ qkv) {
  const int LDQ = 3072;
  int bid = blockIdx.x;
  int pair = bid & 1;
  int nbh = bid >> 1;
  int nb = nbh >> 4, h = nbh & 15;
  int rowblk = nb << 9;
  int tid = threadIdx.x, lane = tid & 63, wave = tid >> 6;
  int g = lane >> 4, cx = lane & 15;

  __shared__ unsigned short sK[64 * 64];
  __shared__ unsigned short sVT[64 * 64];
  __shared__ unsigned short sP[4][32 * 64];
  unsigned short* myP = sP[wave];

  const unsigned short* srcK[2];
  const unsigned short* srcV[2];
  unsigned short* dstK[2];
  int kr_[2], d8_[2];
#pragma unroll
  for (int i = 0; i < 2; ++i) {
    int c = i * 256 + tid;
    int r = c >> 3, pc = c & 7, cc = pc ^ (r & 7);
    srcK[i] = qkv + (size_t)(rowblk + r) * LDQ + 1024 + h * 64 + cc * 8;
    srcV[i] = qkv + (size_t)(rowblk + r) * LDQ + 2048 + h * 64 + pc * 8;
    dstK[i] = sK + (i * 256 + wave * 64) * 8;
    kr_[i] = r; d8_[i] = pc;
  }

  int qa = pair ? 1 : 0;
  int qb = pair ? 2 : 3;
  int ntiles = 2 * qb + 2;  // 8 (pair 0) or 6 (pair 1)

  int qbase[4];
  qbase[0] = qa * 128 + wave * 16;
  qbase[1] = qbase[0] + 64;
  qbase[2] = qb * 128 + wave * 16;
  qbase[3] = qbase[2] + 64;

  short8 qreg[4][2];
#pragma unroll
  for (int f = 0; f < 4; ++f) {
    int qrow = rowblk + qbase[f] + cx;
    const unsigned short* qp = qkv + (size_t)qrow * LDQ + h * 64 + g * 8;
    qreg[f][0] = *(const short8*)qp;
    qreg[f][1] = *(const short8*)(qp + 32);
  }

  f32x4 zero4 = {0.f, 0.f, 0.f, 0.f};
  f32x4 ot[4][4];
#pragma unroll
  for (int a = 0; a < 4; ++a)
#pragma unroll
    for (int b = 0; b < 4; ++b) ot[a][b] = zero4;
  float m_run[4] = {-1e30f, -1e30f, -1e30f, -1e30f};
  float l_run[4] = {0.f, 0.f, 0.f, 0.f};

  const float CEXP = 0.125f * 1.44269504088896f;  // SCALE2 * log2(e)

  for (int t = 0; t < ntiles; ++t) {
    size_t tadv = (size_t)(t * 64) * LDQ;
    short8 vv0 = *(const short8*)(srcV[0] + tadv);
    short8 vv1 = *(const short8*)(srcV[1] + tadv);
    GLOAD_LDS16(srcK[0] + tadv, dstK[0]);
    GLOAD_LDS16(srcK[1] + tadv, dstK[1]);
#pragma unroll
    for (int j = 0; j < 8; ++j) {
      int d0 = d8_[0] * 8 + j, d1 = d8_[1] * 8 + j;
      unsigned o0 = (unsigned)(d0 * 128 + kr_[0] * 2) ^
                    (unsigned)((((d8_[0] ^ j) & 7)) << 4);
      unsigned o1 = (unsigned)(d1 * 128 + kr_[1] * 2) ^
                    (unsigned)((((d8_[1] ^ j) & 7)) << 4);
      *(unsigned short*)((char*)sVT + o0) = (unsigned short)vv0[j];
      *(unsigned short*)((char*)sVT + o1) = (unsigned short)vv1[j];
    }
    __syncthreads();

    bool actA = t <= 2 * qa + 1;

#pragma unroll
    for (int halfq = 0; halfq < 2; ++halfq) {
      if (halfq == 0 && !actA) continue;
      int f0 = halfq * 2;  // frags f0 (ni=0), f0+1 (ni=1)
      bool live0 = (t * 64) <= (qbase[f0] + 15);

      // S^T = K * Q^T (rows k, cols q) for this quarter's 2 frags
      f32x4 s[4][2];
#pragma unroll
      for (int a = 0; a < 4; ++a)
#pragma unroll
        for (int b = 0; b < 2; ++b) s[a][b] = zero4;
#pragma unroll
      for (int ks = 0; ks < 2; ++ks) {
        short8 kf[4];
#pragma unroll
        for (int mi = 0; mi < 4; ++mi) {
          int row = mi * 16 + cx;
          unsigned off = (unsigned)(row * 128 + ks * 64 + g * 16);
          off ^= (unsigned)((row & 7) << 4);
          kf[mi] = *(const short8*)((const char*)sK + off);
        }
        if (live0) {
#pragma unroll
          for (int mi = 0; mi < 4; ++mi)
            s[mi][0] = mfma16(kf[mi], qreg[f0][ks], s[mi][0]);
        }
#pragma unroll
        for (int mi = 0; mi < 4; ++mi)
          s[mi][1] = mfma16(kf[mi], qreg[f0 + 1][ks], s[mi][1]);
      }

      // online softmax per live frag (lane's q = qbase + cx)
      float rescv[2] = {1.f, 1.f};
#pragma unroll
      for (int ni = 0; ni < 2; ++ni) {
        if (ni == 0 && !live0) continue;
        int fi = f0 + ni;
        int qloc = qbase[fi] + cx;
        if ((t * 64 + 63) > qbase[fi]) {  // diagonal tile: causal mask
#pragma unroll
          for (int mi = 0; mi < 4; ++mi)
#pragma unroll
            for (int ri = 0; ri < 4; ++ri) {
              int kk = t * 64 + mi * 16 + g * 4 + ri;
              if (kk > qloc) s[mi][ni][ri] = -3e38f;
            }
        }
        float tm = -3e38f;
#pragma unroll
        for (int mi = 0; mi < 4; ++mi)
          tm = fmaxf(tm, fmaxf(fmaxf(s[mi][ni][0], s[mi][ni][1]),
                               fmaxf(s[mi][ni][2], s[mi][ni][3])));
        tm = fmaxf(tm, __shfl_xor(tm, 16));
        tm = fmaxf(tm, __shfl_xor(tm, 32));
        float mnew = fmaxf(m_run[fi], tm);
        float resc = exp2f((m_run[fi] - mnew) * CEXP);
        float tsum = 0.f;
#pragma unroll
        for (int mi = 0; mi < 4; ++mi)
#pragma unroll
          for (int ri = 0; ri < 4; ++ri) {
            float p = exp2f((s[mi][ni][ri] - mnew) * CEXP);
            s[mi][ni][ri] = p;
            tsum += p;
          }
        tsum += __shfl_xor(tsum, 16);
        tsum += __shfl_xor(tsum, 32);
        l_run[fi] = l_run[fi] * resc + tsum;
        m_run[fi] = mnew;
        rescv[ni] = resc;
      }

      // rescale O^T (lane-local) + P -> per-wave LDS (swizzled)
#pragma unroll
      for (int ni = 0; ni < 2; ++ni) {
        if (ni == 0 && !live0) continue;
        int fi = f0 + ni;
#pragma unroll
        for (int nd = 0; nd < 4; ++nd) {
          ot[fi][nd][0] *= rescv[ni]; ot[fi][nd][1] *= rescv[ni];
          ot[fi][nd][2] *= rescv[ni]; ot[fi][nd][3] *= rescv[ni];
        }
#pragma unroll
        for (int mi = 0; mi < 4; ++mi) {
          ushort4v pk;
          pk[0] = f2bf(s[mi][ni][0]); pk[1] = f2bf(s[mi][ni][1]);
          pk[2] = f2bf(s[mi][ni][2]); pk[3] = f2bf(s[mi][ni][3]);
          int row = ni * 16 + cx;
          unsigned off = (unsigned)(row * 128 + mi * 32 + g * 8);
          off ^= (unsigned)((row & 7) << 4);
          *(ushort4v*)((char*)myP + off) = pk;
        }
      }

      // O^T += V^T * P^T
#pragma unroll
      for (int ks = 0; ks < 2; ++ks) {
        short8 vf[4];
#pragma unroll
        for (int nd = 0; nd < 4; ++nd) {
          int d = nd * 16 + cx;
          unsigned off = (unsigned)(d * 128 + ks * 64 + g * 16);
          off ^= (unsigned)((((d >> 3) ^ d) & 7) << 4);
          vf[nd] = *(const short8*)((const char*)sVT + off);
        }
#pragma unroll
        for (int mq = 0; mq < 2; ++mq) {
          if (mq == 0 && !live0) continue;
          int fi = f0 + mq;
          int row = mq * 16 + cx;
          unsigned off = (unsigned)(row * 128 + ks * 64 + g * 16);
          off ^= (unsigned)((row & 7) << 4);
          short8 pb = *(const short8*)((const char*)myP + off);
#pragma unroll
          for (int nd = 0; nd < 4; ++nd)
            ot[fi][nd] = mfma16(vf[nd], pb, ot[fi][nd]);
        }
      }
    }
    __syncthreads();
  }

  // epilogue: all 4 frags, O^T /= l — lane-local; ushort4 stores
#pragma unroll
  for (int f = 0; f < 4; ++f) {
    float linv = 1.0f / fmaxf(l_run[f], 1e-30f);
    int qrow = rowblk + qbase[f] + cx;
#pragma unroll
    for (int nd = 0; nd < 4; ++nd) {
      ushort4v w4;
      w4[0] = f2bf(ot[f][nd][0] * linv); w4[1] = f2bf(ot[f][nd][1] * linv);
      w4[2] = f2bf(ot[f][nd][2] * linv); w4[3] = f2bf(ot[f][nd][3] * linv);
      int col = h * 64 + nd * 16 + g * 4;
      *(ushort4v*)(qkv + (size_t)qrow * LDQ + col) = w4;
    }
  }
}

// ---------------------------------------------------------------------------
extern "C" void kernel_launch(void* const* d_in, const int* in_sizes, int n_in,
                              void* d_out, int out_size, void* d_ws, size_t ws_size,
                              hipStream_t stream) {
  const float* x      = (const float*)d_in[0];  // [16384,1024] f32
  const float* w_attn = (const float*)d_in[1];  // [1024,3072]  f32
  const float* b_attn = (const float*)d_in[2];  // [3072]       f32
  const float* w_proj = (const float*)d_in[3];  // [1024,1024]  f32
  const float* b_proj = (const float*)d_in[4];  // [1024]       f32
  float* out = (float*)d_out;                   // [16384,1024] f32

  char* ws = (char*)d_ws;
  unsigned short* qkv = (unsigned short*)ws;                       // bf16 16384*3072
  unsigned short* wAT = (unsigned short*)(ws + (size_t)16384 * 3072 * 2);
  unsigned short* wPT = wAT + (size_t)3072 * 1024;
  unsigned short* xbf = (unsigned short*)d_out;  // scratch, dead before GEMM2

  transposeW<<<dim3(48, 16), 256, 0, stream>>>(w_attn, wAT, 1024, 3072);
  transposeW<<<dim3(16, 16), 256, 0, stream>>>(w_proj, wPT, 1024, 1024);
  convert_bf16<<<2048, 256, 0, stream>>>(x, xbf, 16384 * 1024 / 8);

  // qkv = x @ w_attn + b_attn  (C bf16)  M=16384 N=3072 K=1024 -> 64x12 tiles
  gemm256<false><<<768, 512, 0, stream>>>(
      xbf, 1024, wAT, 1024, b_attn, (void*)qkv, 3072, 12, 1024);

  // block-causal attention in-place (1024 merged-quarter blocks)
  attn_block<<<1024, 256, 0, stream>>>(qkv);

  // out = a @ w_proj + b_proj  (C f32)  M=16384 N=1024 K=1024 -> 64x4 tiles
  gemm256<true><<<256, 512, 0, stream>>>(
      qkv, 3072, wPT, 1024, b_proj, (void*)out, 1024, 4, 1024);
}

// Round 16
// 246.651 us; speedup vs baseline: 1.1362x; 1.1362x over previous
//
#include <hip/hip_runtime.h>
#include <stdint.h>

// FactoredAttention: x[16384,1024] f32 -> (x->bf16) -> qkv GEMM -> 16-block
// causal attn -> proj GEMM -> out f32.  I/O f32; bf16 compute/intermediates.
// ws: qkv bf16 (16384*3072) | w_attnT bf16 (3072*1024) | w_projT bf16 (1024*1024)
// xbf16 (33.5MB) lives in d_out scratch (dead before GEMM2 writes it).
// R16: REVERT to R12 (best measured, 245.8us).  R15's merged-quarter attn
// regressed (VGPR 84->148, occupancy 20->11% — attn is occupancy-bound).
// gemm256 = R12 4-phase + per-phase staging; attn = R7 (84 VGPR, 5 blk/CU,
// conflict-free V^T scatter, paired quarters).

typedef __bf16 bf16x8 __attribute__((ext_vector_type(8)));
typedef short short8 __attribute__((ext_vector_type(8)));
typedef float f32x4 __attribute__((ext_vector_type(4)));
typedef unsigned short ushort4v __attribute__((ext_vector_type(4)));
typedef unsigned short ushort8v __attribute__((ext_vector_type(8)));

#define GLOAD_LDS16(g, l)                                                      \
  __builtin_amdgcn_global_load_lds(                                            \
      (const __attribute__((address_space(1))) void*)(g),                      \
      (__attribute__((address_space(3))) void*)(l), 16, 0, 0)

static __device__ __forceinline__ f32x4 mfma16(short8 a, short8 b, f32x4 c) {
  return __builtin_amdgcn_mfma_f32_16x16x32_bf16(
      __builtin_bit_cast(bf16x8, a), __builtin_bit_cast(bf16x8, b), c, 0, 0, 0);
}

static __device__ __forceinline__ unsigned short f2bf(float f) {
  unsigned u = __builtin_bit_cast(unsigned, f);
  u += 0x7FFFu + ((u >> 16) & 1u);
  return (unsigned short)(u >> 16);
}

// ---------------------------------------------------------------------------
// f32 -> bf16 elementwise convert (vectorized, grid-stride).
// ---------------------------------------------------------------------------
__global__ __launch_bounds__(256) void convert_bf16(
    const float* __restrict__ in, unsigned short* __restrict__ out, int n8) {
  for (int i = blockIdx.x * 256 + threadIdx.x; i < n8; i += gridDim.x * 256) {
    f32x4 lo = *(const f32x4*)(in + (size_t)i * 8);
    f32x4 hi = *(const f32x4*)(in + (size_t)i * 8 + 4);
    ushort8v v;
    v[0] = f2bf(lo[0]); v[1] = f2bf(lo[1]); v[2] = f2bf(lo[2]); v[3] = f2bf(lo[3]);
    v[4] = f2bf(hi[0]); v[5] = f2bf(hi[1]); v[6] = f2bf(hi[2]); v[7] = f2bf(hi[3]);
    *(ushort8v*)(out + (size_t)i * 8) = v;
  }
}

// ---------------------------------------------------------------------------
// Transpose + convert: in f32 [K][N] -> out bf16 [N][K].  grid (N/64, K/64).
// ---------------------------------------------------------------------------
__global__ __launch_bounds__(256) void transposeW(
    const float* __restrict__ in, unsigned short* __restrict__ out,
    int K, int N) {
  __shared__ float tile[64][68];
  int tn = blockIdx.x * 64, tk = blockIdx.y * 64;
  int tid = threadIdx.x;
#pragma unroll
  for (int i = 0; i < 4; ++i) {
    int ch = i * 256 + tid;
    int r = ch >> 4, c4 = (ch & 15) << 2;
    f32x4 v = *(const f32x4*)(in + (size_t)(tk + r) * N + tn + c4);
    tile[r][c4] = v[0]; tile[r][c4 + 1] = v[1];
    tile[r][c4 + 2] = v[2]; tile[r][c4 + 3] = v[3];
  }
  __syncthreads();
#pragma unroll
  for (int i = 0; i < 4; ++i) {
    int ch = i * 256 + tid;
    int r = ch >> 4, c4 = (ch & 15) << 2;
    ushort4v v;
    v[0] = f2bf(tile[c4][r]);     v[1] = f2bf(tile[c4 + 1][r]);
    v[2] = f2bf(tile[c4 + 2][r]); v[3] = f2bf(tile[c4 + 3][r]);
    *(ushort4v*)(out + (size_t)(tn + r) * K + tk + c4) = v;
  }
}

// ---------------------------------------------------------------------------
// C[M][N] = A[M][K] * Bt[N][K]^T + bias(f32).  A,Bt bf16.  (R12 verbatim)
// 256x256 tile, BK=64, 512 threads (2M x 4N waves, 128x64 out each).
// LDS double-buffer (128KB).  Per K-tile: vmcnt(0) handoff (all outstanding =
// this tile's stages, issued during the previous tile's phases), then 4
// quadrant phases, each:
//   {ds_read A-quad 4xb128 [+B 8xb128 in phase0]; 2x global_load_lds for
//    next tile's quarter q; [phase0: lgkmcnt(8)]; s_barrier; lgkmcnt(0)+
//    sched_barrier; setprio(1); 16 MFMA; setprio(0); s_barrier}
// Swizzle byte ^= (row&7)<<4 with inverse-swizzled global source (0-conflict).
// grid.x % 8 == 0 (XCD swizzle).
// ---------------------------------------------------------------------------
template <bool C_F32>
__global__ __launch_bounds__(512, 2) void gemm256(
    const unsigned short* __restrict__ A, int lda,
    const unsigned short* __restrict__ Bt, int ldb,
    const float* __restrict__ bias,
    void* __restrict__ Cptr, int ldc,
    int Ntiles, int K) {
  __shared__ unsigned short sA[2][256 * 64];
  __shared__ unsigned short sB[2][256 * 64];
  int bid = blockIdx.x;
  int nwg = gridDim.x;
  int swz = (bid & 7) * (nwg >> 3) + (bid >> 3);
  int bm = swz / Ntiles, bn = swz % Ntiles;
  int tid = threadIdx.x;
  int lane = tid & 63, wave = tid >> 6;
  int wr = wave >> 2, wc = wave & 3;  // 2M x 4N wave grid
  int g = lane >> 4, cx = lane & 15;

  const unsigned short* srcA[4];
  const unsigned short* srcB[4];
  int dstoff[4];
#pragma unroll
  for (int i = 0; i < 4; ++i) {
    int c = i * 512 + tid;
    int r = c >> 3, pc = c & 7;
    int cc = pc ^ (r & 7);  // inverse-swizzled source chunk
    srcA[i] = A + (size_t)(bm * 256 + r) * lda + cc * 8;
    srcB[i] = Bt + (size_t)(bn * 256 + r) * ldb + cc * 8;
    dstoff[i] = (i * 512 + wave * 64) * 8;
  }

  f32x4 zero4 = {0.f, 0.f, 0.f, 0.f};
  f32x4 acc[8][4];
#pragma unroll
  for (int a = 0; a < 8; ++a)
#pragma unroll
    for (int b = 0; b < 4; ++b) acc[a][b] = zero4;

  int NT = K >> 6;

  // prologue: stage tile 0 into buffer 0 in consumption order
  GLOAD_LDS16(srcB[0], sB[0] + dstoff[0]);
  GLOAD_LDS16(srcB[1], sB[0] + dstoff[1]);
  GLOAD_LDS16(srcB[2], sB[0] + dstoff[2]);
  GLOAD_LDS16(srcB[3], sB[0] + dstoff[3]);
  GLOAD_LDS16(srcA[0], sA[0] + dstoff[0]);
  GLOAD_LDS16(srcA[2], sA[0] + dstoff[2]);
  GLOAD_LDS16(srcA[1], sA[0] + dstoff[1]);
  GLOAD_LDS16(srcA[3], sA[0] + dstoff[3]);

  for (int t = 0; t < NT; ++t) {
    int p = t & 1;
    // tile-top handoff: all outstanding VMEM = this tile's stages
    asm volatile("s_waitcnt vmcnt(0)" ::: "memory");
    __builtin_amdgcn_sched_barrier(0);
    __builtin_amdgcn_s_barrier();
    __builtin_amdgcn_sched_barrier(0);

    const char* bA = (const char*)sA[p];
    const char* bB = (const char*)sB[p];
    unsigned short* nA = sA[p ^ 1];
    unsigned short* nB = sB[p ^ 1];
    bool pre = (t + 1 < NT);
    int kt = (t + 1) * 64;
    short8 bfr[4][2];

#define READ_A(afv, q)                                                         \
  _Pragma("unroll") for (int mm = 0; mm < 2; ++mm)                             \
      _Pragma("unroll") for (int ks = 0; ks < 2; ++ks) {                       \
    int row = wr * 128 + ((q) * 2 + mm) * 16 + cx;                             \
    unsigned off = (unsigned)(row * 128 + ks * 64 + g * 16) ^                  \
                   ((unsigned)(row & 7) << 4);                                 \
    afv[mm][ks] = *(const short8*)(bA + off);                                  \
  }
#define MFMA_Q(afv, q)                                                         \
  __builtin_amdgcn_s_setprio(1);                                               \
  _Pragma("unroll") for (int mm = 0; mm < 2; ++mm)                             \
      _Pragma("unroll") for (int ni = 0; ni < 4; ++ni)                         \
          _Pragma("unroll") for (int ks = 0; ks < 2; ++ks)                     \
      acc[(q) * 2 + mm][ni] =                                                  \
          mfma16(afv[mm][ks], bfr[ni][ks], acc[(q) * 2 + mm][ni]);             \
  __builtin_amdgcn_s_setprio(0);
#define PHASE_TAIL()                                                           \
  __builtin_amdgcn_sched_barrier(0);                                           \
  __builtin_amdgcn_s_barrier();                                                \
  asm volatile("s_waitcnt lgkmcnt(0)" ::: "memory");                           \
  __builtin_amdgcn_sched_barrier(0);
#define PHASE_END()                                                            \
  __builtin_amdgcn_sched_barrier(0);                                           \
  __builtin_amdgcn_s_barrier();                                                \
  __builtin_amdgcn_sched_barrier(0);

    // ---- phase 0: B full + A quad0; stage B0',B1' ----
    {
#pragma unroll
      for (int ni = 0; ni < 4; ++ni)
#pragma unroll
        for (int ks = 0; ks < 2; ++ks) {
          int row = wc * 64 + ni * 16 + cx;
          unsigned off = (unsigned)(row * 128 + ks * 64 + g * 16) ^
                         ((unsigned)(row & 7) << 4);
          bfr[ni][ks] = *(const short8*)(bB + off);
        }
      short8 af[2][2];
      READ_A(af, 0);
      if (pre) {
        GLOAD_LDS16(srcB[0] + kt, nB + dstoff[0]);
        GLOAD_LDS16(srcB[1] + kt, nB + dstoff[1]);
      }
      asm volatile("s_waitcnt lgkmcnt(8)" ::: "memory");
      PHASE_TAIL();
      MFMA_Q(af, 0);
      PHASE_END();
    }
    // ---- phase 1: A quad1; stage B2',B3' ----
    {
      short8 af[2][2];
      READ_A(af, 1);
      if (pre) {
        GLOAD_LDS16(srcB[2] + kt, nB + dstoff[2]);
        GLOAD_LDS16(srcB[3] + kt, nB + dstoff[3]);
      }
      PHASE_TAIL();
      MFMA_Q(af, 1);
      PHASE_END();
    }
    // ---- phase 2: A quad2; stage A0',A2' ----
    {
      short8 af[2][2];
      READ_A(af, 2);
      if (pre) {
        GLOAD_LDS16(srcA[0] + kt, nA + dstoff[0]);
        GLOAD_LDS16(srcA[2] + kt, nA + dstoff[2]);
      }
      PHASE_TAIL();
      MFMA_Q(af, 2);
      PHASE_END();
    }
    // ---- phase 3: A quad3; stage A1',A3' ----
    {
      short8 af[2][2];
      READ_A(af, 3);
      if (pre) {
        GLOAD_LDS16(srcA[1] + kt, nA + dstoff[1]);
        GLOAD_LDS16(srcA[3] + kt, nA + dstoff[3]);
      }
      PHASE_TAIL();
      MFMA_Q(af, 3);
      PHASE_END();
    }
#undef READ_A
#undef MFMA_Q
#undef PHASE_TAIL
#undef PHASE_END
  }

  float bv[4];
#pragma unroll
  for (int ni = 0; ni < 4; ++ni)
    bv[ni] = bias[bn * 256 + wc * 64 + ni * 16 + cx];

#pragma unroll
  for (int mi = 0; mi < 8; ++mi)
#pragma unroll
    for (int ni = 0; ni < 4; ++ni) {
      int col = bn * 256 + wc * 64 + ni * 16 + cx;
#pragma unroll
      for (int ri = 0; ri < 4; ++ri) {
        int row = bm * 256 + wr * 128 + mi * 16 + g * 4 + ri;
        float v = acc[mi][ni][ri] + bv[ni];
        if (C_F32)
          ((float*)Cptr)[(size_t)row * ldc + col] = v;
        else
          ((unsigned short*)Cptr)[(size_t)row * ldc + col] = f2bf(v);
      }
    }
}

// ---------------------------------------------------------------------------
// Block-causal flash attention, in-place (O overwrites q slice of qkv).
// grid: 32 nb * 16 h * 2 pairs = 1024 blocks, 4 waves.  (R7 verbatim)
// Block (nb,h,pair) processes quarters {0,3} (pair 0) or {1,2} (pair 1)
// sequentially -> uniform 10 tile-iterations per block (no dispatch tail).
// S^T = mfma(K, Q) -> softmax lane-local at q = lane&15; O^T = mfma(V^T, P^T)
// keeps q lane-local (no shfl rescale/epilogue).
// sVT swizzle: byte = (d*128 + 2k) ^ (((d>>3)^d)&7)<<4 -> conflict-free
// scatter writes AND optimal b128 reads.  LDS 32KB -> 5 blocks/CU, 84 VGPR.
// ---------------------------------------------------------------------------
__global__ __launch_bounds__(256) void attn_block(unsigned short* __restrict__ qkv) {
  const int LDQ = 3072;
  int bid = blockIdx.x;
  int pair = bid & 1;
  int nbh = bid >> 1;
  int nb = nbh >> 4, h = nbh & 15;
  int rowblk = nb << 9;
  int tid = threadIdx.x, lane = tid & 63, wave = tid >> 6;
  int g = lane >> 4, cx = lane & 15;

  __shared__ unsigned short sK[64 * 64];
  __shared__ unsigned short sVT[64 * 64];
  __shared__ unsigned short sP[4][32 * 64];
  unsigned short* myP = sP[wave];

  const unsigned short* srcK[2];
  const unsigned short* srcV[2];
  unsigned short* dstK[2];
  int kr_[2], d8_[2];
#pragma unroll
  for (int i = 0; i < 2; ++i) {
    int c = i * 256 + tid;
    int r = c >> 3, pc = c & 7, cc = pc ^ (r & 7);
    srcK[i] = qkv + (size_t)(rowblk + r) * LDQ + 1024 + h * 64 + cc * 8;
    srcV[i] = qkv + (size_t)(rowblk + r) * LDQ + 2048 + h * 64 + pc * 8;
    dstK[i] = sK + (i * 256 + wave * 64) * 8;
    kr_[i] = r; d8_[i] = pc;
  }

  f32x4 zero4 = {0.f, 0.f, 0.f, 0.f};
  const float CEXP = 0.125f * 1.44269504088896f;  // SCALE2 * log2(e)

  for (int qq = 0; qq < 2; ++qq) {
    int qs = qq ? (pair ? 2 : 3) : (pair ? 1 : 0);
    int ntiles = 2 * qs + 2;
    int qb0 = qs * 128 + wave * 16;

    short8 qreg[2][2];
#pragma unroll
    for (int ni = 0; ni < 2; ++ni) {
      int qrow = rowblk + qb0 + ni * 64 + cx;
      const unsigned short* qp = qkv + (size_t)qrow * LDQ + h * 64 + g * 8;
      qreg[ni][0] = *(const short8*)qp;
      qreg[ni][1] = *(const short8*)(qp + 32);
    }

    f32x4 ot[2][4];
#pragma unroll
    for (int a = 0; a < 2; ++a)
#pragma unroll
      for (int b = 0; b < 4; ++b) ot[a][b] = zero4;
    float m_run[2] = {-1e30f, -1e30f};
    float l_run[2] = {0.f, 0.f};

    for (int t = 0; t < ntiles; ++t) {
      size_t tadv = (size_t)(t * 64) * LDQ;
      short8 vv0 = *(const short8*)(srcV[0] + tadv);
      short8 vv1 = *(const short8*)(srcV[1] + tadv);
      GLOAD_LDS16(srcK[0] + tadv, dstK[0]);
      GLOAD_LDS16(srcK[1] + tadv, dstK[1]);
#pragma unroll
      for (int j = 0; j < 8; ++j) {
        int d0 = d8_[0] * 8 + j, d1 = d8_[1] * 8 + j;
        unsigned o0 = (unsigned)(d0 * 128 + kr_[0] * 2) ^
                      (unsigned)((((d8_[0] ^ j) & 7)) << 4);
        unsigned o1 = (unsigned)(d1 * 128 + kr_[1] * 2) ^
                      (unsigned)((((d8_[1] ^ j) & 7)) << 4);
        *(unsigned short*)((char*)sVT + o0) = (unsigned short)vv0[j];
        *(unsigned short*)((char*)sVT + o1) = (unsigned short)vv1[j];
      }
      __syncthreads();

      bool live0 = (t * 64) <= (qb0 + 15);

      f32x4 s[4][2];
#pragma unroll
      for (int a = 0; a < 4; ++a)
#pragma unroll
        for (int b = 0; b < 2; ++b) s[a][b] = zero4;
#pragma unroll
      for (int ks = 0; ks < 2; ++ks) {
        short8 kf[4];
#pragma unroll
        for (int mi = 0; mi < 4; ++mi) {
          int row = mi * 16 + cx;
          unsigned off = (unsigned)(row * 128 + ks * 64 + g * 16);
          off ^= (unsigned)((row & 7) << 4);
          kf[mi] = *(const short8*)((const char*)sK + off);
        }
        if (live0) {
#pragma unroll
          for (int mi = 0; mi < 4; ++mi)
            s[mi][0] = mfma16(kf[mi], qreg[0][ks], s[mi][0]);
        }
#pragma unroll
        for (int mi = 0; mi < 4; ++mi)
          s[mi][1] = mfma16(kf[mi], qreg[1][ks], s[mi][1]);
      }

      float rescv[2] = {1.f, 1.f};
#pragma unroll
      for (int ni = 0; ni < 2; ++ni) {
        if (ni == 0 && !live0) continue;
        int qbase = qb0 + ni * 64;
        int qloc = qbase + cx;
        if ((t * 64 + 63) > qbase) {
#pragma unroll
          for (int mi = 0; mi < 4; ++mi)
#pragma unroll
            for (int ri = 0; ri < 4; ++ri) {
              int kk = t * 64 + mi * 16 + g * 4 + ri;
              if (kk > qloc) s[mi][ni][ri] = -3e38f;
            }
        }
        float tm = -3e38f;
#pragma unroll
        for (int mi = 0; mi < 4; ++mi)
          tm = fmaxf(tm, fmaxf(fmaxf(s[mi][ni][0], s[mi][ni][1]),
                               fmaxf(s[mi][ni][2], s[mi][ni][3])));
        tm = fmaxf(tm, __shfl_xor(tm, 16));
        tm = fmaxf(tm, __shfl_xor(tm, 32));
        float mnew = fmaxf(m_run[ni], tm);
        float resc = exp2f((m_run[ni] - mnew) * CEXP);
        float tsum = 0.f;
#pragma unroll
        for (int mi = 0; mi < 4; ++mi)
#pragma unroll
          for (int ri = 0; ri < 4; ++ri) {
            float p = exp2f((s[mi][ni][ri] - mnew) * CEXP);
            s[mi][ni][ri] = p;
            tsum += p;
          }
        tsum += __shfl_xor(tsum, 16);
        tsum += __shfl_xor(tsum, 32);
        l_run[ni] = l_run[ni] * resc + tsum;
        m_run[ni] = mnew;
        rescv[ni] = resc;
      }

#pragma unroll
      for (int ni = 0; ni < 2; ++ni) {
        if (ni == 0 && !live0) continue;
#pragma unroll
        for (int nd = 0; nd < 4; ++nd) {
          ot[ni][nd][0] *= rescv[ni]; ot[ni][nd][1] *= rescv[ni];
          ot[ni][nd][2] *= rescv[ni]; ot[ni][nd][3] *= rescv[ni];
        }
#pragma unroll
        for (int mi = 0; mi < 4; ++mi) {
          ushort4v pk;
          pk[0] = f2bf(s[mi][ni][0]); pk[1] = f2bf(s[mi][ni][1]);
          pk[2] = f2bf(s[mi][ni][2]); pk[3] = f2bf(s[mi][ni][3]);
          int row = ni * 16 + cx;
          unsigned off = (unsigned)(row * 128 + mi * 32 + g * 8);
          off ^= (unsigned)((row & 7) << 4);
          *(ushort4v*)((char*)myP + off) = pk;
        }
      }

#pragma unroll
      for (int ks = 0; ks < 2; ++ks) {
        short8 vf[4];
#pragma unroll
        for (int nd = 0; nd < 4; ++nd) {
          int d = nd * 16 + cx;
          unsigned off = (unsigned)(d * 128 + ks * 64 + g * 16);
          off ^= (unsigned)((((d >> 3) ^ d) & 7) << 4);
          vf[nd] = *(const short8*)((const char*)sVT + off);
        }
#pragma unroll
        for (int mq = 0; mq < 2; ++mq) {
          if (mq == 0 && !live0) continue;
          int row = mq * 16 + cx;
          unsigned off = (unsigned)(row * 128 + ks * 64 + g * 16);
          off ^= (unsigned)((row & 7) << 4);
          short8 pb = *(const short8*)((const char*)myP + off);
#pragma unroll
          for (int nd = 0; nd < 4; ++nd)
            ot[mq][nd] = mfma16(vf[nd], pb, ot[mq][nd]);
        }
      }
      __syncthreads();
    }

#pragma unroll
    for (int mq = 0; mq < 2; ++mq) {
      float linv = 1.0f / fmaxf(l_run[mq], 1e-30f);
      int qrow = rowblk + qb0 + mq * 64 + cx;
#pragma unroll
      for (int nd = 0; nd < 4; ++nd) {
        ushort4v w4;
        w4[0] = f2bf(ot[mq][nd][0] * linv); w4[1] = f2bf(ot[mq][nd][1] * linv);
        w4[2] = f2bf(ot[mq][nd][2] * linv); w4[3] = f2bf(ot[mq][nd][3] * linv);
        int col = h * 64 + nd * 16 + g * 4;
        *(ushort4v*)(qkv + (size_t)qrow * LDQ + col) = w4;
      }
    }
  }
}

// ---------------------------------------------------------------------------
extern "C" void kernel_launch(void* const* d_in, const int* in_sizes, int n_in,
                              void* d_out, int out_size, void* d_ws, size_t ws_size,
                              hipStream_t stream) {
  const float* x      = (const float*)d_in[0];  // [16384,1024] f32
  const float* w_attn = (const float*)d_in[1];  // [1024,3072]  f32
  const float* b_attn = (const float*)d_in[2];  // [3072]       f32
  const float* w_proj = (const float*)d_in[3];  // [1024,1024]  f32
  const float* b_proj = (const float*)d_in[4];  // [1024]       f32
  float* out = (float*)d_out;                   // [16384,1024] f32

  char* ws = (char*)d_ws;
  unsigned short* qkv = (unsigned short*)ws;                       // bf16 16384*3072
  unsigned short* wAT = (unsigned short*)(ws + (size_t)16384 * 3072 * 2);
  unsigned short* wPT = wAT + (size_t)3072 * 1024;
  unsigned short* xbf = (unsigned short*)d_out;  // scratch, dead before GEMM2

  transposeW<<<dim3(48, 16), 256, 0, stream>>>(w_attn, wAT, 1024, 3072);
  transposeW<<<dim3(16, 16), 256, 0, stream>>>(w_proj, wPT, 1024, 1024);
  convert_bf16<<<2048, 256, 0, stream>>>(x, xbf, 16384 * 1024 / 8);

  // qkv = x @ w_attn + b_attn  (C bf16)  M=16384 N=3072 K=1024 -> 64x12 tiles
  gemm256<false><<<768, 512, 0, stream>>>(
      xbf, 1024, wAT, 1024, b_attn, (void*)qkv, 3072, 12, 1024);

  // block-causal attention in-place (1024 uniform blocks of paired quarters)
  attn_block<<<1024, 256, 0, stream>>>(qkv);

  // out = a @ w_proj + b_proj  (C f32)  M=16384 N=1024 K=1024 -> 64x4 tiles
  gemm256<true><<<256, 512, 0, stream>>>(
      qkv, 3072, wPT, 1024, b_proj, (void*)out, 1024, 4, 1024);
}

// Round 17
// 245.267 us; speedup vs baseline: 1.1426x; 1.0056x over previous
//
#include <hip/hip_runtime.h>
#include <stdint.h>

// FactoredAttention: x[16384,1024] f32 -> (x->bf16) -> qkv GEMM -> 16-block
// causal attn -> proj GEMM -> out f32.  I/O f32; bf16 compute/intermediates.
// ws: qkv bf16 (16384*3072) | w_attnT bf16 (3072*1024) | w_projT bf16 (1024*1024)
// xbf16 (33.5MB) lives in d_out scratch (dead before GEMM2 writes it).
// R17: R16 (best, 246us) + merged weight-transpose launch (one kernel handles
// both w_attn and w_proj via flattened grid) — removes one dispatch.
// gemm256 = R12 4-phase + per-phase staging (845 TF plateau, stable across
// R12/R14/R16); attn = R7 (84 VGPR, 5 blk/CU, conflict-free V^T).

typedef __bf16 bf16x8 __attribute__((ext_vector_type(8)));
typedef short short8 __attribute__((ext_vector_type(8)));
typedef float f32x4 __attribute__((ext_vector_type(4)));
typedef unsigned short ushort4v __attribute__((ext_vector_type(4)));
typedef unsigned short ushort8v __attribute__((ext_vector_type(8)));

#define GLOAD_LDS16(g, l)                                                      \
  __builtin_amdgcn_global_load_lds(                                            \
      (const __attribute__((address_space(1))) void*)(g),                      \
      (__attribute__((address_space(3))) void*)(l), 16, 0, 0)

static __device__ __forceinline__ f32x4 mfma16(short8 a, short8 b, f32x4 c) {
  return __builtin_amdgcn_mfma_f32_16x16x32_bf16(
      __builtin_bit_cast(bf16x8, a), __builtin_bit_cast(bf16x8, b), c, 0, 0, 0);
}

static __device__ __forceinline__ unsigned short f2bf(float f) {
  unsigned u = __builtin_bit_cast(unsigned, f);
  u += 0x7FFFu + ((u >> 16) & 1u);
  return (unsigned short)(u >> 16);
}

// ---------------------------------------------------------------------------
// f32 -> bf16 elementwise convert (vectorized, grid-stride).
// ---------------------------------------------------------------------------
__global__ __launch_bounds__(256) void convert_bf16(
    const float* __restrict__ in, unsigned short* __restrict__ out, int n8) {
  for (int i = blockIdx.x * 256 + threadIdx.x; i < n8; i += gridDim.x * 256) {
    f32x4 lo = *(const f32x4*)(in + (size_t)i * 8);
    f32x4 hi = *(const f32x4*)(in + (size_t)i * 8 + 4);
    ushort8v v;
    v[0] = f2bf(lo[0]); v[1] = f2bf(lo[1]); v[2] = f2bf(lo[2]); v[3] = f2bf(lo[3]);
    v[4] = f2bf(hi[0]); v[5] = f2bf(hi[1]); v[6] = f2bf(hi[2]); v[7] = f2bf(hi[3]);
    *(ushort8v*)(out + (size_t)i * 8) = v;
  }
}

// ---------------------------------------------------------------------------
// Merged transpose+convert for BOTH weights: f32 [K][N] -> bf16 [N][K].
// grid.x = 48 (w_attn N-tiles) + 16 (w_proj N-tiles); grid.y = 16 (K-tiles).
// ---------------------------------------------------------------------------
__global__ __launch_bounds__(256) void transposeW2(
    const float* __restrict__ wA, unsigned short* __restrict__ oA,
    const float* __restrict__ wP, unsigned short* __restrict__ oP) {
  __shared__ float tile[64][68];
  int bx = blockIdx.x;
  const float* in;
  unsigned short* out;
  int N;
  if (bx < 48) { in = wA; out = oA; N = 3072; }
  else         { in = wP; out = oP; N = 1024; bx -= 48; }
  const int K = 1024;
  int tn = bx * 64, tk = blockIdx.y * 64;
  int tid = threadIdx.x;
#pragma unroll
  for (int i = 0; i < 4; ++i) {
    int ch = i * 256 + tid;
    int r = ch >> 4, c4 = (ch & 15) << 2;
    f32x4 v = *(const f32x4*)(in + (size_t)(tk + r) * N + tn + c4);
    tile[r][c4] = v[0]; tile[r][c4 + 1] = v[1];
    tile[r][c4 + 2] = v[2]; tile[r][c4 + 3] = v[3];
  }
  __syncthreads();
#pragma unroll
  for (int i = 0; i < 4; ++i) {
    int ch = i * 256 + tid;
    int r = ch >> 4, c4 = (ch & 15) << 2;
    ushort4v v;
    v[0] = f2bf(tile[c4][r]);     v[1] = f2bf(tile[c4 + 1][r]);
    v[2] = f2bf(tile[c4 + 2][r]); v[3] = f2bf(tile[c4 + 3][r]);
    *(ushort4v*)(out + (size_t)(tn + r) * K + tk + c4) = v;
  }
}

// ---------------------------------------------------------------------------
// C[M][N] = A[M][K] * Bt[N][K]^T + bias(f32).  A,Bt bf16.  (R12 verbatim)
// 256x256 tile, BK=64, 512 threads (2M x 4N waves, 128x64 out each).
// LDS double-buffer (128KB).  Per K-tile: vmcnt(0) handoff (all outstanding =
// this tile's stages, issued during the previous tile's phases), then 4
// quadrant phases, each:
//   {ds_read A-quad 4xb128 [+B 8xb128 in phase0]; 2x global_load_lds for
//    next tile's quarter q; [phase0: lgkmcnt(8)]; s_barrier; lgkmcnt(0)+
//    sched_barrier; setprio(1); 16 MFMA; setprio(0); s_barrier}
// Swizzle byte ^= (row&7)<<4 with inverse-swizzled global source (0-conflict).
// grid.x % 8 == 0 (XCD swizzle).
// ---------------------------------------------------------------------------
template <bool C_F32>
__global__ __launch_bounds__(512, 2) void gemm256(
    const unsigned short* __restrict__ A, int lda,
    const unsigned short* __restrict__ Bt, int ldb,
    const float* __restrict__ bias,
    void* __restrict__ Cptr, int ldc,
    int Ntiles, int K) {
  __shared__ unsigned short sA[2][256 * 64];
  __shared__ unsigned short sB[2][256 * 64];
  int bid = blockIdx.x;
  int nwg = gridDim.x;
  int swz = (bid & 7) * (nwg >> 3) + (bid >> 3);
  int bm = swz / Ntiles, bn = swz % Ntiles;
  int tid = threadIdx.x;
  int lane = tid & 63, wave = tid >> 6;
  int wr = wave >> 2, wc = wave & 3;  // 2M x 4N wave grid
  int g = lane >> 4, cx = lane & 15;

  const unsigned short* srcA[4];
  const unsigned short* srcB[4];
  int dstoff[4];
#pragma unroll
  for (int i = 0; i < 4; ++i) {
    int c = i * 512 + tid;
    int r = c >> 3, pc = c & 7;
    int cc = pc ^ (r & 7);  // inverse-swizzled source chunk
    srcA[i] = A + (size_t)(bm * 256 + r) * lda + cc * 8;
    srcB[i] = Bt + (size_t)(bn * 256 + r) * ldb + cc * 8;
    dstoff[i] = (i * 512 + wave * 64) * 8;
  }

  f32x4 zero4 = {0.f, 0.f, 0.f, 0.f};
  f32x4 acc[8][4];
#pragma unroll
  for (int a = 0; a < 8; ++a)
#pragma unroll
    for (int b = 0; b < 4; ++b) acc[a][b] = zero4;

  int NT = K >> 6;

  // prologue: stage tile 0 into buffer 0 in consumption order
  GLOAD_LDS16(srcB[0], sB[0] + dstoff[0]);
  GLOAD_LDS16(srcB[1], sB[0] + dstoff[1]);
  GLOAD_LDS16(srcB[2], sB[0] + dstoff[2]);
  GLOAD_LDS16(srcB[3], sB[0] + dstoff[3]);
  GLOAD_LDS16(srcA[0], sA[0] + dstoff[0]);
  GLOAD_LDS16(srcA[2], sA[0] + dstoff[2]);
  GLOAD_LDS16(srcA[1], sA[0] + dstoff[1]);
  GLOAD_LDS16(srcA[3], sA[0] + dstoff[3]);

  for (int t = 0; t < NT; ++t) {
    int p = t & 1;
    // tile-top handoff: all outstanding VMEM = this tile's stages
    asm volatile("s_waitcnt vmcnt(0)" ::: "memory");
    __builtin_amdgcn_sched_barrier(0);
    __builtin_amdgcn_s_barrier();
    __builtin_amdgcn_sched_barrier(0);

    const char* bA = (const char*)sA[p];
    const char* bB = (const char*)sB[p];
    unsigned short* nA = sA[p ^ 1];
    unsigned short* nB = sB[p ^ 1];
    bool pre = (t + 1 < NT);
    int kt = (t + 1) * 64;
    short8 bfr[4][2];

#define READ_A(afv, q)                                                         \
  _Pragma("unroll") for (int mm = 0; mm < 2; ++mm)                             \
      _Pragma("unroll") for (int ks = 0; ks < 2; ++ks) {                       \
    int row = wr * 128 + ((q) * 2 + mm) * 16 + cx;                             \
    unsigned off = (unsigned)(row * 128 + ks * 64 + g * 16) ^                  \
                   ((unsigned)(row & 7) << 4);                                 \
    afv[mm][ks] = *(const short8*)(bA + off);                                  \
  }
#define MFMA_Q(afv, q)                                                         \
  __builtin_amdgcn_s_setprio(1);                                               \
  _Pragma("unroll") for (int mm = 0; mm < 2; ++mm)                             \
      _Pragma("unroll") for (int ni = 0; ni < 4; ++ni)                         \
          _Pragma("unroll") for (int ks = 0; ks < 2; ++ks)                     \
      acc[(q) * 2 + mm][ni] =                                                  \
          mfma16(afv[mm][ks], bfr[ni][ks], acc[(q) * 2 + mm][ni]);             \
  __builtin_amdgcn_s_setprio(0);
#define PHASE_TAIL()                                                           \
  __builtin_amdgcn_sched_barrier(0);                                           \
  __builtin_amdgcn_s_barrier();                                                \
  asm volatile("s_waitcnt lgkmcnt(0)" ::: "memory");                           \
  __builtin_amdgcn_sched_barrier(0);
#define PHASE_END()                                                            \
  __builtin_amdgcn_sched_barrier(0);                                           \
  __builtin_amdgcn_s_barrier();                                                \
  __builtin_amdgcn_sched_barrier(0);

    // ---- phase 0: B full + A quad0; stage B0',B1' ----
    {
#pragma unroll
      for (int ni = 0; ni < 4; ++ni)
#pragma unroll
        for (int ks = 0; ks < 2; ++ks) {
          int row = wc * 64 + ni * 16 + cx;
          unsigned off = (unsigned)(row * 128 + ks * 64 + g * 16) ^
                         ((unsigned)(row & 7) << 4);
          bfr[ni][ks] = *(const short8*)(bB + off);
        }
      short8 af[2][2];
      READ_A(af, 0);
      if (pre) {
        GLOAD_LDS16(srcB[0] + kt, nB + dstoff[0]);
        GLOAD_LDS16(srcB[1] + kt, nB + dstoff[1]);
      }
      asm volatile("s_waitcnt lgkmcnt(8)" ::: "memory");
      PHASE_TAIL();
      MFMA_Q(af, 0);
      PHASE_END();
    }
    // ---- phase 1: A quad1; stage B2',B3' ----
    {
      short8 af[2][2];
      READ_A(af, 1);
      if (pre) {
        GLOAD_LDS16(srcB[2] + kt, nB + dstoff[2]);
        GLOAD_LDS16(srcB[3] + kt, nB + dstoff[3]);
      }
      PHASE_TAIL();
      MFMA_Q(af, 1);
      PHASE_END();
    }
    // ---- phase 2: A quad2; stage A0',A2' ----
    {
      short8 af[2][2];
      READ_A(af, 2);
      if (pre) {
        GLOAD_LDS16(srcA[0] + kt, nA + dstoff[0]);
        GLOAD_LDS16(srcA[2] + kt, nA + dstoff[2]);
      }
      PHASE_TAIL();
      MFMA_Q(af, 2);
      PHASE_END();
    }
    // ---- phase 3: A quad3; stage A1',A3' ----
    {
      short8 af[2][2];
      READ_A(af, 3);
      if (pre) {
        GLOAD_LDS16(srcA[1] + kt, nA + dstoff[1]);
        GLOAD_LDS16(srcA[3] + kt, nA + dstoff[3]);
      }
      PHASE_TAIL();
      MFMA_Q(af, 3);
      PHASE_END();
    }
#undef READ_A
#undef MFMA_Q
#undef PHASE_TAIL
#undef PHASE_END
  }

  float bv[4];
#pragma unroll
  for (int ni = 0; ni < 4; ++ni)
    bv[ni] = bias[bn * 256 + wc * 64 + ni * 16 + cx];

#pragma unroll
  for (int mi = 0; mi < 8; ++mi)
#pragma unroll
    for (int ni = 0; ni < 4; ++ni) {
      int col = bn * 256 + wc * 64 + ni * 16 + cx;
#pragma unroll
      for (int ri = 0; ri < 4; ++ri) {
        int row = bm * 256 + wr * 128 + mi * 16 + g * 4 + ri;
        float v = acc[mi][ni][ri] + bv[ni];
        if (C_F32)
          ((float*)Cptr)[(size_t)row * ldc + col] = v;
        else
          ((unsigned short*)Cptr)[(size_t)row * ldc + col] = f2bf(v);
      }
    }
}

// ---------------------------------------------------------------------------
// Block-causal flash attention, in-place (O overwrites q slice of qkv).
// grid: 32 nb * 16 h * 2 pairs = 1024 blocks, 4 waves.  (R7 verbatim)
// Block (nb,h,pair) processes quarters {0,3} (pair 0) or {1,2} (pair 1)
// sequentially -> uniform 10 tile-iterations per block (no dispatch tail).
// S^T = mfma(K, Q) -> softmax lane-local at q = lane&15; O^T = mfma(V^T, P^T)
// keeps q lane-local (no shfl rescale/epilogue).
// sVT swizzle: byte = (d*128 + 2k) ^ (((d>>3)^d)&7)<<4 -> conflict-free
// scatter writes AND optimal b128 reads.  LDS 32KB -> 5 blocks/CU, 84 VGPR.
// ---------------------------------------------------------------------------
__global__ __launch_bounds__(256) void attn_block(unsigned short* __restrict__ qkv) {
  const int LDQ = 3072;
  int bid = blockIdx.x;
  int pair = bid & 1;
  int nbh = bid >> 1;
  int nb = nbh >> 4, h = nbh & 15;
  int rowblk = nb << 9;
  int tid = threadIdx.x, lane = tid & 63, wave = tid >> 6;
  int g = lane >> 4, cx = lane & 15;

  __shared__ unsigned short sK[64 * 64];
  __shared__ unsigned short sVT[64 * 64];
  __shared__ unsigned short sP[4][32 * 64];
  unsigned short* myP = sP[wave];

  const unsigned short* srcK[2];
  const unsigned short* srcV[2];
  unsigned short* dstK[2];
  int kr_[2], d8_[2];
#pragma unroll
  for (int i = 0; i < 2; ++i) {
    int c = i * 256 + tid;
    int r = c >> 3, pc = c & 7, cc = pc ^ (r & 7);
    srcK[i] = qkv + (size_t)(rowblk + r) * LDQ + 1024 + h * 64 + cc * 8;
    srcV[i] = qkv + (size_t)(rowblk + r) * LDQ + 2048 + h * 64 + pc * 8;
    dstK[i] = sK + (i * 256 + wave * 64) * 8;
    kr_[i] = r; d8_[i] = pc;
  }

  f32x4 zero4 = {0.f, 0.f, 0.f, 0.f};
  const float CEXP = 0.125f * 1.44269504088896f;  // SCALE2 * log2(e)

  for (int qq = 0; qq < 2; ++qq) {
    int qs = qq ? (pair ? 2 : 3) : (pair ? 1 : 0);
    int ntiles = 2 * qs + 2;
    int qb0 = qs * 128 + wave * 16;

    short8 qreg[2][2];
#pragma unroll
    for (int ni = 0; ni < 2; ++ni) {
      int qrow = rowblk + qb0 + ni * 64 + cx;
      const unsigned short* qp = qkv + (size_t)qrow * LDQ + h * 64 + g * 8;
      qreg[ni][0] = *(const short8*)qp;
      qreg[ni][1] = *(const short8*)(qp + 32);
    }

    f32x4 ot[2][4];
#pragma unroll
    for (int a = 0; a < 2; ++a)
#pragma unroll
      for (int b = 0; b < 4; ++b) ot[a][b] = zero4;
    float m_run[2] = {-1e30f, -1e30f};
    float l_run[2] = {0.f, 0.f};

    for (int t = 0; t < ntiles; ++t) {
      size_t tadv = (size_t)(t * 64) * LDQ;
      short8 vv0 = *(const short8*)(srcV[0] + tadv);
      short8 vv1 = *(const short8*)(srcV[1] + tadv);
      GLOAD_LDS16(srcK[0] + tadv, dstK[0]);
      GLOAD_LDS16(srcK[1] + tadv, dstK[1]);
#pragma unroll
      for (int j = 0; j < 8; ++j) {
        int d0 = d8_[0] * 8 + j, d1 = d8_[1] * 8 + j;
        unsigned o0 = (unsigned)(d0 * 128 + kr_[0] * 2) ^
                      (unsigned)((((d8_[0] ^ j) & 7)) << 4);
        unsigned o1 = (unsigned)(d1 * 128 + kr_[1] * 2) ^
                      (unsigned)((((d8_[1] ^ j) & 7)) << 4);
        *(unsigned short*)((char*)sVT + o0) = (unsigned short)vv0[j];
        *(unsigned short*)((char*)sVT + o1) = (unsigned short)vv1[j];
      }
      __syncthreads();

      bool live0 = (t * 64) <= (qb0 + 15);

      f32x4 s[4][2];
#pragma unroll
      for (int a = 0; a < 4; ++a)
#pragma unroll
        for (int b = 0; b < 2; ++b) s[a][b] = zero4;
#pragma unroll
      for (int ks = 0; ks < 2; ++ks) {
        short8 kf[4];
#pragma unroll
        for (int mi = 0; mi < 4; ++mi) {
          int row = mi * 16 + cx;
          unsigned off = (unsigned)(row * 128 + ks * 64 + g * 16);
          off ^= (unsigned)((row & 7) << 4);
          kf[mi] = *(const short8*)((const char*)sK + off);
        }
        if (live0) {
#pragma unroll
          for (int mi = 0; mi < 4; ++mi)
            s[mi][0] = mfma16(kf[mi], qreg[0][ks], s[mi][0]);
        }
#pragma unroll
        for (int mi = 0; mi < 4; ++mi)
          s[mi][1] = mfma16(kf[mi], qreg[1][ks], s[mi][1]);
      }

      float rescv[2] = {1.f, 1.f};
#pragma unroll
      for (int ni = 0; ni < 2; ++ni) {
        if (ni == 0 && !live0) continue;
        int qbase = qb0 + ni * 64;
        int qloc = qbase + cx;
        if ((t * 64 + 63) > qbase) {
#pragma unroll
          for (int mi = 0; mi < 4; ++mi)
#pragma unroll
            for (int ri = 0; ri < 4; ++ri) {
              int kk = t * 64 + mi * 16 + g * 4 + ri;
              if (kk > qloc) s[mi][ni][ri] = -3e38f;
            }
        }
        float tm = -3e38f;
#pragma unroll
        for (int mi = 0; mi < 4; ++mi)
          tm = fmaxf(tm, fmaxf(fmaxf(s[mi][ni][0], s[mi][ni][1]),
                               fmaxf(s[mi][ni][2], s[mi][ni][3])));
        tm = fmaxf(tm, __shfl_xor(tm, 16));
        tm = fmaxf(tm, __shfl_xor(tm, 32));
        float mnew = fmaxf(m_run[ni], tm);
        float resc = exp2f((m_run[ni] - mnew) * CEXP);
        float tsum = 0.f;
#pragma unroll
        for (int mi = 0; mi < 4; ++mi)
#pragma unroll
          for (int ri = 0; ri < 4; ++ri) {
            float p = exp2f((s[mi][ni][ri] - mnew) * CEXP);
            s[mi][ni][ri] = p;
            tsum += p;
          }
        tsum += __shfl_xor(tsum, 16);
        tsum += __shfl_xor(tsum, 32);
        l_run[ni] = l_run[ni] * resc + tsum;
        m_run[ni] = mnew;
        rescv[ni] = resc;
      }

#pragma unroll
      for (int ni = 0; ni < 2; ++ni) {
        if (ni == 0 && !live0) continue;
#pragma unroll
        for (int nd = 0; nd < 4; ++nd) {
          ot[ni][nd][0] *= rescv[ni]; ot[ni][nd][1] *= rescv[ni];
          ot[ni][nd][2] *= rescv[ni]; ot[ni][nd][3] *= rescv[ni];
        }
#pragma unroll
        for (int mi = 0; mi < 4; ++mi) {
          ushort4v pk;
          pk[0] = f2bf(s[mi][ni][0]); pk[1] = f2bf(s[mi][ni][1]);
          pk[2] = f2bf(s[mi][ni][2]); pk[3] = f2bf(s[mi][ni][3]);
          int row = ni * 16 + cx;
          unsigned off = (unsigned)(row * 128 + mi * 32 + g * 8);
          off ^= (unsigned)((row & 7) << 4);
          *(ushort4v*)((char*)myP + off) = pk;
        }
      }

#pragma unroll
      for (int ks = 0; ks < 2; ++ks) {
        short8 vf[4];
#pragma unroll
        for (int nd = 0; nd < 4; ++nd) {
          int d = nd * 16 + cx;
          unsigned off = (unsigned)(d * 128 + ks * 64 + g * 16);
          off ^= (unsigned)((((d >> 3) ^ d) & 7) << 4);
          vf[nd] = *(const short8*)((const char*)sVT + off);
        }
#pragma unroll
        for (int mq = 0; mq < 2; ++mq) {
          if (mq == 0 && !live0) continue;
          int row = mq * 16 + cx;
          unsigned off = (unsigned)(row * 128 + ks * 64 + g * 16);
          off ^= (unsigned)((row & 7) << 4);
          short8 pb = *(const short8*)((const char*)myP + off);
#pragma unroll
          for (int nd = 0; nd < 4; ++nd)
            ot[mq][nd] = mfma16(vf[nd], pb, ot[mq][nd]);
        }
      }
      __syncthreads();
    }

#pragma unroll
    for (int mq = 0; mq < 2; ++mq) {
      float linv = 1.0f / fmaxf(l_run[mq], 1e-30f);
      int qrow = rowblk + qb0 + mq * 64 + cx;
#pragma unroll
      for (int nd = 0; nd < 4; ++nd) {
        ushort4v w4;
        w4[0] = f2bf(ot[mq][nd][0] * linv); w4[1] = f2bf(ot[mq][nd][1] * linv);
        w4[2] = f2bf(ot[mq][nd][2] * linv); w4[3] = f2bf(ot[mq][nd][3] * linv);
        int col = h * 64 + nd * 16 + g * 4;
        *(ushort4v*)(qkv + (size_t)qrow * LDQ + col) = w4;
      }
    }
  }
}

// ---------------------------------------------------------------------------
extern "C" void kernel_launch(void* const* d_in, const int* in_sizes, int n_in,
                              void* d_out, int out_size, void* d_ws, size_t ws_size,
                              hipStream_t stream) {
  const float* x      = (const float*)d_in[0];  // [16384,1024] f32
  const float* w_attn = (const float*)d_in[1];  // [1024,3072]  f32
  const float* b_attn = (const float*)d_in[2];  // [3072]       f32
  const float* w_proj = (const float*)d_in[3];  // [1024,1024]  f32
  const float* b_proj = (const float*)d_in[4];  // [1024]       f32
  float* out = (float*)d_out;                   // [16384,1024] f32

  char* ws = (char*)d_ws;
  unsigned short* qkv = (unsigned short*)ws;                       // bf16 16384*3072
  unsigned short* wAT = (unsigned short*)(ws + (size_t)16384 * 3072 * 2);
  unsigned short* wPT = wAT + (size_t)3072 * 1024;
  unsigned short* xbf = (unsigned short*)d_out;  // scratch, dead before GEMM2

  // merged weight transposes (one launch) + x convert
  transposeW2<<<dim3(64, 16), 256, 0, stream>>>(w_attn, wAT, w_proj, wPT);
  convert_bf16<<<2048, 256, 0, stream>>>(x, xbf, 16384 * 1024 / 8);

  // qkv = x @ w_attn + b_attn  (C bf16)  M=16384 N=3072 K=1024 -> 64x12 tiles
  gemm256<false><<<768, 512, 0, stream>>>(
      xbf, 1024, wAT, 1024, b_attn, (void*)qkv, 3072, 12, 1024);

  // block-causal attention in-place (1024 uniform blocks of paired quarters)
  attn_block<<<1024, 256, 0, stream>>>(qkv);

  // out = a @ w_proj + b_proj  (C f32)  M=16384 N=1024 K=1024 -> 64x4 tiles
  gemm256<true><<<256, 512, 0, stream>>>(
      qkv, 3072, wPT, 1024, b_proj, (void*)out, 1024, 4, 1024);
}

// Round 18
// 237.197 us; speedup vs baseline: 1.1815x; 1.0340x over previous
//
#include <hip/hip_runtime.h>
#include <stdint.h>

// FactoredAttention: x[16384,1024] f32 -> (x->bf16) -> qkv GEMM -> 16-block
// causal attn -> proj GEMM -> out f32.  I/O f32; bf16 compute/intermediates.
// ws: qkv bf16 (16384*3072) | w_attnT bf16 (3072*1024) | w_projT bf16 (1024*1024)
// xbf16 (33.5MB) lives in d_out scratch (dead before GEMM2 writes it).
// R18: R17 + attn re-split into 2048 single-quarter blocks with LONGEST-FIRST
// dispatch (qs = 3 - bid>>9): per-CU greedy-LPT makespan ~8 tile-units vs 10
// for the 1024-uniform-block pairing (5 slots/CU, 8 blocks/CU of 2/4/6/8
// tiles).  Kernel body = R7 verbatim (32KB LDS, conflict-free V^T, dead-frag
// skip).  GEMMs/convert/transpose unchanged from R17.

typedef __bf16 bf16x8 __attribute__((ext_vector_type(8)));
typedef short short8 __attribute__((ext_vector_type(8)));
typedef float f32x4 __attribute__((ext_vector_type(4)));
typedef unsigned short ushort4v __attribute__((ext_vector_type(4)));
typedef unsigned short ushort8v __attribute__((ext_vector_type(8)));

#define GLOAD_LDS16(g, l)                                                      \
  __builtin_amdgcn_global_load_lds(                                            \
      (const __attribute__((address_space(1))) void*)(g),                      \
      (__attribute__((address_space(3))) void*)(l), 16, 0, 0)

static __device__ __forceinline__ f32x4 mfma16(short8 a, short8 b, f32x4 c) {
  return __builtin_amdgcn_mfma_f32_16x16x32_bf16(
      __builtin_bit_cast(bf16x8, a), __builtin_bit_cast(bf16x8, b), c, 0, 0, 0);
}

static __device__ __forceinline__ unsigned short f2bf(float f) {
  unsigned u = __builtin_bit_cast(unsigned, f);
  u += 0x7FFFu + ((u >> 16) & 1u);
  return (unsigned short)(u >> 16);
}

// ---------------------------------------------------------------------------
// f32 -> bf16 elementwise convert (vectorized, grid-stride).
// ---------------------------------------------------------------------------
__global__ __launch_bounds__(256) void convert_bf16(
    const float* __restrict__ in, unsigned short* __restrict__ out, int n8) {
  for (int i = blockIdx.x * 256 + threadIdx.x; i < n8; i += gridDim.x * 256) {
    f32x4 lo = *(const f32x4*)(in + (size_t)i * 8);
    f32x4 hi = *(const f32x4*)(in + (size_t)i * 8 + 4);
    ushort8v v;
    v[0] = f2bf(lo[0]); v[1] = f2bf(lo[1]); v[2] = f2bf(lo[2]); v[3] = f2bf(lo[3]);
    v[4] = f2bf(hi[0]); v[5] = f2bf(hi[1]); v[6] = f2bf(hi[2]); v[7] = f2bf(hi[3]);
    *(ushort8v*)(out + (size_t)i * 8) = v;
  }
}

// ---------------------------------------------------------------------------
// Merged transpose+convert for BOTH weights: f32 [K][N] -> bf16 [N][K].
// grid.x = 48 (w_attn N-tiles) + 16 (w_proj N-tiles); grid.y = 16 (K-tiles).
// ---------------------------------------------------------------------------
__global__ __launch_bounds__(256) void transposeW2(
    const float* __restrict__ wA, unsigned short* __restrict__ oA,
    const float* __restrict__ wP, unsigned short* __restrict__ oP) {
  __shared__ float tile[64][68];
  int bx = blockIdx.x;
  const float* in;
  unsigned short* out;
  int N;
  if (bx < 48) { in = wA; out = oA; N = 3072; }
  else         { in = wP; out = oP; N = 1024; bx -= 48; }
  const int K = 1024;
  int tn = bx * 64, tk = blockIdx.y * 64;
  int tid = threadIdx.x;
#pragma unroll
  for (int i = 0; i < 4; ++i) {
    int ch = i * 256 + tid;
    int r = ch >> 4, c4 = (ch & 15) << 2;
    f32x4 v = *(const f32x4*)(in + (size_t)(tk + r) * N + tn + c4);
    tile[r][c4] = v[0]; tile[r][c4 + 1] = v[1];
    tile[r][c4 + 2] = v[2]; tile[r][c4 + 3] = v[3];
  }
  __syncthreads();
#pragma unroll
  for (int i = 0; i < 4; ++i) {
    int ch = i * 256 + tid;
    int r = ch >> 4, c4 = (ch & 15) << 2;
    ushort4v v;
    v[0] = f2bf(tile[c4][r]);     v[1] = f2bf(tile[c4 + 1][r]);
    v[2] = f2bf(tile[c4 + 2][r]); v[3] = f2bf(tile[c4 + 3][r]);
    *(ushort4v*)(out + (size_t)(tn + r) * K + tk + c4) = v;
  }
}

// ---------------------------------------------------------------------------
// C[M][N] = A[M][K] * Bt[N][K]^T + bias(f32).  A,Bt bf16.  (R12 verbatim)
// 256x256 tile, BK=64, 512 threads (2M x 4N waves, 128x64 out each).
// LDS double-buffer (128KB).  Per K-tile: vmcnt(0) handoff, then 4 quadrant
// phases with per-phase staging of next tile's quarters.
// Swizzle byte ^= (row&7)<<4 with inverse-swizzled global source (0-conflict).
// grid.x % 8 == 0 (XCD swizzle).
// ---------------------------------------------------------------------------
template <bool C_F32>
__global__ __launch_bounds__(512, 2) void gemm256(
    const unsigned short* __restrict__ A, int lda,
    const unsigned short* __restrict__ Bt, int ldb,
    const float* __restrict__ bias,
    void* __restrict__ Cptr, int ldc,
    int Ntiles, int K) {
  __shared__ unsigned short sA[2][256 * 64];
  __shared__ unsigned short sB[2][256 * 64];
  int bid = blockIdx.x;
  int nwg = gridDim.x;
  int swz = (bid & 7) * (nwg >> 3) + (bid >> 3);
  int bm = swz / Ntiles, bn = swz % Ntiles;
  int tid = threadIdx.x;
  int lane = tid & 63, wave = tid >> 6;
  int wr = wave >> 2, wc = wave & 3;  // 2M x 4N wave grid
  int g = lane >> 4, cx = lane & 15;

  const unsigned short* srcA[4];
  const unsigned short* srcB[4];
  int dstoff[4];
#pragma unroll
  for (int i = 0; i < 4; ++i) {
    int c = i * 512 + tid;
    int r = c >> 3, pc = c & 7;
    int cc = pc ^ (r & 7);  // inverse-swizzled source chunk
    srcA[i] = A + (size_t)(bm * 256 + r) * lda + cc * 8;
    srcB[i] = Bt + (size_t)(bn * 256 + r) * ldb + cc * 8;
    dstoff[i] = (i * 512 + wave * 64) * 8;
  }

  f32x4 zero4 = {0.f, 0.f, 0.f, 0.f};
  f32x4 acc[8][4];
#pragma unroll
  for (int a = 0; a < 8; ++a)
#pragma unroll
    for (int b = 0; b < 4; ++b) acc[a][b] = zero4;

  int NT = K >> 6;

  // prologue: stage tile 0 into buffer 0 in consumption order
  GLOAD_LDS16(srcB[0], sB[0] + dstoff[0]);
  GLOAD_LDS16(srcB[1], sB[0] + dstoff[1]);
  GLOAD_LDS16(srcB[2], sB[0] + dstoff[2]);
  GLOAD_LDS16(srcB[3], sB[0] + dstoff[3]);
  GLOAD_LDS16(srcA[0], sA[0] + dstoff[0]);
  GLOAD_LDS16(srcA[2], sA[0] + dstoff[2]);
  GLOAD_LDS16(srcA[1], sA[0] + dstoff[1]);
  GLOAD_LDS16(srcA[3], sA[0] + dstoff[3]);

  for (int t = 0; t < NT; ++t) {
    int p = t & 1;
    // tile-top handoff: all outstanding VMEM = this tile's stages
    asm volatile("s_waitcnt vmcnt(0)" ::: "memory");
    __builtin_amdgcn_sched_barrier(0);
    __builtin_amdgcn_s_barrier();
    __builtin_amdgcn_sched_barrier(0);

    const char* bA = (const char*)sA[p];
    const char* bB = (const char*)sB[p];
    unsigned short* nA = sA[p ^ 1];
    unsigned short* nB = sB[p ^ 1];
    bool pre = (t + 1 < NT);
    int kt = (t + 1) * 64;
    short8 bfr[4][2];

#define READ_A(afv, q)                                                         \
  _Pragma("unroll") for (int mm = 0; mm < 2; ++mm)                             \
      _Pragma("unroll") for (int ks = 0; ks < 2; ++ks) {                       \
    int row = wr * 128 + ((q) * 2 + mm) * 16 + cx;                             \
    unsigned off = (unsigned)(row * 128 + ks * 64 + g * 16) ^                  \
                   ((unsigned)(row & 7) << 4);                                 \
    afv[mm][ks] = *(const short8*)(bA + off);                                  \
  }
#define MFMA_Q(afv, q)                                                         \
  __builtin_amdgcn_s_setprio(1);                                               \
  _Pragma("unroll") for (int mm = 0; mm < 2; ++mm)                             \
      _Pragma("unroll") for (int ni = 0; ni < 4; ++ni)                         \
          _Pragma("unroll") for (int ks = 0; ks < 2; ++ks)                     \
      acc[(q) * 2 + mm][ni] =                                                  \
          mfma16(afv[mm][ks], bfr[ni][ks], acc[(q) * 2 + mm][ni]);             \
  __builtin_amdgcn_s_setprio(0);
#define PHASE_TAIL()                                                           \
  __builtin_amdgcn_sched_barrier(0);                                           \
  __builtin_amdgcn_s_barrier();                                                \
  asm volatile("s_waitcnt lgkmcnt(0)" ::: "memory");                           \
  __builtin_amdgcn_sched_barrier(0);
#define PHASE_END()                                                            \
  __builtin_amdgcn_sched_barrier(0);                                           \
  __builtin_amdgcn_s_barrier();                                                \
  __builtin_amdgcn_sched_barrier(0);

    // ---- phase 0: B full + A quad0; stage B0',B1' ----
    {
#pragma unroll
      for (int ni = 0; ni < 4; ++ni)
#pragma unroll
        for (int ks = 0; ks < 2; ++ks) {
          int row = wc * 64 + ni * 16 + cx;
          unsigned off = (unsigned)(row * 128 + ks * 64 + g * 16) ^
                         ((unsigned)(row & 7) << 4);
          bfr[ni][ks] = *(const short8*)(bB + off);
        }
      short8 af[2][2];
      READ_A(af, 0);
      if (pre) {
        GLOAD_LDS16(srcB[0] + kt, nB + dstoff[0]);
        GLOAD_LDS16(srcB[1] + kt, nB + dstoff[1]);
      }
      asm volatile("s_waitcnt lgkmcnt(8)" ::: "memory");
      PHASE_TAIL();
      MFMA_Q(af, 0);
      PHASE_END();
    }
    // ---- phase 1: A quad1; stage B2',B3' ----
    {
      short8 af[2][2];
      READ_A(af, 1);
      if (pre) {
        GLOAD_LDS16(srcB[2] + kt, nB + dstoff[2]);
        GLOAD_LDS16(srcB[3] + kt, nB + dstoff[3]);
      }
      PHASE_TAIL();
      MFMA_Q(af, 1);
      PHASE_END();
    }
    // ---- phase 2: A quad2; stage A0',A2' ----
    {
      short8 af[2][2];
      READ_A(af, 2);
      if (pre) {
        GLOAD_LDS16(srcA[0] + kt, nA + dstoff[0]);
        GLOAD_LDS16(srcA[2] + kt, nA + dstoff[2]);
      }
      PHASE_TAIL();
      MFMA_Q(af, 2);
      PHASE_END();
    }
    // ---- phase 3: A quad3; stage A1',A3' ----
    {
      short8 af[2][2];
      READ_A(af, 3);
      if (pre) {
        GLOAD_LDS16(srcA[1] + kt, nA + dstoff[1]);
        GLOAD_LDS16(srcA[3] + kt, nA + dstoff[3]);
      }
      PHASE_TAIL();
      MFMA_Q(af, 3);
      PHASE_END();
    }
#undef READ_A
#undef MFMA_Q
#undef PHASE_TAIL
#undef PHASE_END
  }

  float bv[4];
#pragma unroll
  for (int ni = 0; ni < 4; ++ni)
    bv[ni] = bias[bn * 256 + wc * 64 + ni * 16 + cx];

#pragma unroll
  for (int mi = 0; mi < 8; ++mi)
#pragma unroll
    for (int ni = 0; ni < 4; ++ni) {
      int col = bn * 256 + wc * 64 + ni * 16 + cx;
#pragma unroll
      for (int ri = 0; ri < 4; ++ri) {
        int row = bm * 256 + wr * 128 + mi * 16 + g * 4 + ri;
        float v = acc[mi][ni][ri] + bv[ni];
        if (C_F32)
          ((float*)Cptr)[(size_t)row * ldc + col] = v;
        else
          ((unsigned short*)Cptr)[(size_t)row * ldc + col] = f2bf(v);
      }
    }
}

// ---------------------------------------------------------------------------
// Block-causal flash attention, in-place (O overwrites q slice of qkv).
// R18 grid: 2048 single-quarter blocks, LONGEST-FIRST: qs = 3 - (bid>>9),
// (nb,h) = bid & 511.  Body = R7 verbatim (one quarter per block).
// S^T = mfma(K, Q) -> softmax lane-local at q = lane&15; O^T = mfma(V^T, P^T).
// sVT swizzle: byte = (d*128 + 2k) ^ (((d>>3)^d)&7)<<4 (conflict-free both
// sides); K/P swizzle byte ^= (row&7)<<4.  LDS 32KB -> 5 blocks/CU.
// ---------------------------------------------------------------------------
__global__ __launch_bounds__(256) void attn_block(unsigned short* __restrict__ qkv) {
  const int LDQ = 3072;
  int bid = blockIdx.x;
  int qs = 3 - (bid >> 9);          // longest quarters dispatch first
  int nbh = bid & 511;
  int nb = nbh >> 4, h = nbh & 15;
  int rowblk = nb << 9;
  int tid = threadIdx.x, lane = tid & 63, wave = tid >> 6;
  int g = lane >> 4, cx = lane & 15;

  __shared__ unsigned short sK[64 * 64];
  __shared__ unsigned short sVT[64 * 64];
  __shared__ unsigned short sP[4][32 * 64];
  unsigned short* myP = sP[wave];

  const unsigned short* srcK[2];
  const unsigned short* srcV[2];
  unsigned short* dstK[2];
  int kr_[2], d8_[2];
#pragma unroll
  for (int i = 0; i < 2; ++i) {
    int c = i * 256 + tid;
    int r = c >> 3, pc = c & 7, cc = pc ^ (r & 7);
    srcK[i] = qkv + (size_t)(rowblk + r) * LDQ + 1024 + h * 64 + cc * 8;
    srcV[i] = qkv + (size_t)(rowblk + r) * LDQ + 2048 + h * 64 + pc * 8;
    dstK[i] = sK + (i * 256 + wave * 64) * 8;
    kr_[i] = r; d8_[i] = pc;
  }

  f32x4 zero4 = {0.f, 0.f, 0.f, 0.f};
  const float CEXP = 0.125f * 1.44269504088896f;  // SCALE2 * log2(e)

  int ntiles = 2 * qs + 2;
  int qb0 = qs * 128 + wave * 16;

  short8 qreg[2][2];
#pragma unroll
  for (int ni = 0; ni < 2; ++ni) {
    int qrow = rowblk + qb0 + ni * 64 + cx;
    const unsigned short* qp = qkv + (size_t)qrow * LDQ + h * 64 + g * 8;
    qreg[ni][0] = *(const short8*)qp;
    qreg[ni][1] = *(const short8*)(qp + 32);
  }

  f32x4 ot[2][4];
#pragma unroll
  for (int a = 0; a < 2; ++a)
#pragma unroll
    for (int b = 0; b < 4; ++b) ot[a][b] = zero4;
  float m_run[2] = {-1e30f, -1e30f};
  float l_run[2] = {0.f, 0.f};

  for (int t = 0; t < ntiles; ++t) {
    size_t tadv = (size_t)(t * 64) * LDQ;
    short8 vv0 = *(const short8*)(srcV[0] + tadv);
    short8 vv1 = *(const short8*)(srcV[1] + tadv);
    GLOAD_LDS16(srcK[0] + tadv, dstK[0]);
    GLOAD_LDS16(srcK[1] + tadv, dstK[1]);
#pragma unroll
    for (int j = 0; j < 8; ++j) {
      int d0 = d8_[0] * 8 + j, d1 = d8_[1] * 8 + j;
      unsigned o0 = (unsigned)(d0 * 128 + kr_[0] * 2) ^
                    (unsigned)((((d8_[0] ^ j) & 7)) << 4);
      unsigned o1 = (unsigned)(d1 * 128 + kr_[1] * 2) ^
                    (unsigned)((((d8_[1] ^ j) & 7)) << 4);
      *(unsigned short*)((char*)sVT + o0) = (unsigned short)vv0[j];
      *(unsigned short*)((char*)sVT + o1) = (unsigned short)vv1[j];
    }
    __syncthreads();

    bool live0 = (t * 64) <= (qb0 + 15);

    f32x4 s[4][2];
#pragma unroll
    for (int a = 0; a < 4; ++a)
#pragma unroll
      for (int b = 0; b < 2; ++b) s[a][b] = zero4;
#pragma unroll
    for (int ks = 0; ks < 2; ++ks) {
      short8 kf[4];
#pragma unroll
      for (int mi = 0; mi < 4; ++mi) {
        int row = mi * 16 + cx;
        unsigned off = (unsigned)(row * 128 + ks * 64 + g * 16);
        off ^= (unsigned)((row & 7) << 4);
        kf[mi] = *(const short8*)((const char*)sK + off);
      }
      if (live0) {
#pragma unroll
        for (int mi = 0; mi < 4; ++mi)
          s[mi][0] = mfma16(kf[mi], qreg[0][ks], s[mi][0]);
      }
#pragma unroll
      for (int mi = 0; mi < 4; ++mi)
        s[mi][1] = mfma16(kf[mi], qreg[1][ks], s[mi][1]);
    }

    float rescv[2] = {1.f, 1.f};
#pragma unroll
    for (int ni = 0; ni < 2; ++ni) {
      if (ni == 0 && !live0) continue;
      int qbase = qb0 + ni * 64;
      int qloc = qbase + cx;
      if ((t * 64 + 63) > qbase) {
#pragma unroll
        for (int mi = 0; mi < 4; ++mi)
#pragma unroll
          for (int ri = 0; ri < 4; ++ri) {
            int kk = t * 64 + mi * 16 + g * 4 + ri;
            if (kk > qloc) s[mi][ni][ri] = -3e38f;
          }
      }
      float tm = -3e38f;
#pragma unroll
      for (int mi = 0; mi < 4; ++mi)
        tm = fmaxf(tm, fmaxf(fmaxf(s[mi][ni][0], s[mi][ni][1]),
                             fmaxf(s[mi][ni][2], s[mi][ni][3])));
      tm = fmaxf(tm, __shfl_xor(tm, 16));
      tm = fmaxf(tm, __shfl_xor(tm, 32));
      float mnew = fmaxf(m_run[ni], tm);
      float resc = exp2f((m_run[ni] - mnew) * CEXP);
      float tsum = 0.f;
#pragma unroll
      for (int mi = 0; mi < 4; ++mi)
#pragma unroll
        for (int ri = 0; ri < 4; ++ri) {
          float p = exp2f((s[mi][ni][ri] - mnew) * CEXP);
          s[mi][ni][ri] = p;
          tsum += p;
        }
      tsum += __shfl_xor(tsum, 16);
      tsum += __shfl_xor(tsum, 32);
      l_run[ni] = l_run[ni] * resc + tsum;
      m_run[ni] = mnew;
      rescv[ni] = resc;
    }

#pragma unroll
    for (int ni = 0; ni < 2; ++ni) {
      if (ni == 0 && !live0) continue;
#pragma unroll
      for (int nd = 0; nd < 4; ++nd) {
        ot[ni][nd][0] *= rescv[ni]; ot[ni][nd][1] *= rescv[ni];
        ot[ni][nd][2] *= rescv[ni]; ot[ni][nd][3] *= rescv[ni];
      }
#pragma unroll
      for (int mi = 0; mi < 4; ++mi) {
        ushort4v pk;
        pk[0] = f2bf(s[mi][ni][0]); pk[1] = f2bf(s[mi][ni][1]);
        pk[2] = f2bf(s[mi][ni][2]); pk[3] = f2bf(s[mi][ni][3]);
        int row = ni * 16 + cx;
        unsigned off = (unsigned)(row * 128 + mi * 32 + g * 8);
        off ^= (unsigned)((row & 7) << 4);
        *(ushort4v*)((char*)myP + off) = pk;
      }
    }

#pragma unroll
    for (int ks = 0; ks < 2; ++ks) {
      short8 vf[4];
#pragma unroll
      for (int nd = 0; nd < 4; ++nd) {
        int d = nd * 16 + cx;
        unsigned off = (unsigned)(d * 128 + ks * 64 + g * 16);
        off ^= (unsigned)((((d >> 3) ^ d) & 7) << 4);
        vf[nd] = *(const short8*)((const char*)sVT + off);
      }
#pragma unroll
      for (int mq = 0; mq < 2; ++mq) {
        if (mq == 0 && !live0) continue;
        int row = mq * 16 + cx;
        unsigned off = (unsigned)(row * 128 + ks * 64 + g * 16);
        off ^= (unsigned)((row & 7) << 4);
        short8 pb = *(const short8*)((const char*)myP + off);
#pragma unroll
        for (int nd = 0; nd < 4; ++nd)
          ot[mq][nd] = mfma16(vf[nd], pb, ot[mq][nd]);
      }
    }
    __syncthreads();
  }

#pragma unroll
  for (int mq = 0; mq < 2; ++mq) {
    float linv = 1.0f / fmaxf(l_run[mq], 1e-30f);
    int qrow = rowblk + qb0 + mq * 64 + cx;
#pragma unroll
    for (int nd = 0; nd < 4; ++nd) {
      ushort4v w4;
      w4[0] = f2bf(ot[mq][nd][0] * linv); w4[1] = f2bf(ot[mq][nd][1] * linv);
      w4[2] = f2bf(ot[mq][nd][2] * linv); w4[3] = f2bf(ot[mq][nd][3] * linv);
      int col = h * 64 + nd * 16 + g * 4;
      *(ushort4v*)(qkv + (size_t)qrow * LDQ + col) = w4;
    }
  }
}

// ---------------------------------------------------------------------------
extern "C" void kernel_launch(void* const* d_in, const int* in_sizes, int n_in,
                              void* d_out, int out_size, void* d_ws, size_t ws_size,
                              hipStream_t stream) {
  const float* x      = (const float*)d_in[0];  // [16384,1024] f32
  const float* w_attn = (const float*)d_in[1];  // [1024,3072]  f32
  const float* b_attn = (const float*)d_in[2];  // [3072]       f32
  const float* w_proj = (const float*)d_in[3];  // [1024,1024]  f32
  const float* b_proj = (const float*)d_in[4];  // [1024]       f32
  float* out = (float*)d_out;                   // [16384,1024] f32

  char* ws = (char*)d_ws;
  unsigned short* qkv = (unsigned short*)ws;                       // bf16 16384*3072
  unsigned short* wAT = (unsigned short*)(ws + (size_t)16384 * 3072 * 2);
  unsigned short* wPT = wAT + (size_t)3072 * 1024;
  unsigned short* xbf = (unsigned short*)d_out;  // scratch, dead before GEMM2

  transposeW2<<<dim3(64, 16), 256, 0, stream>>>(w_attn, wAT, w_proj, wPT);
  convert_bf16<<<2048, 256, 0, stream>>>(x, xbf, 16384 * 1024 / 8);

  // qkv = x @ w_attn + b_attn  (C bf16)  M=16384 N=3072 K=1024 -> 64x12 tiles
  gemm256<false><<<768, 512, 0, stream>>>(
      xbf, 1024, wAT, 1024, b_attn, (void*)qkv, 3072, 12, 1024);

  // block-causal attention in-place (2048 single-quarter blocks, longest-first)
  attn_block<<<2048, 256, 0, stream>>>(qkv);

  // out = a @ w_proj + b_proj  (C f32)  M=16384 N=1024 K=1024 -> 64x4 tiles
  gemm256<true><<<256, 512, 0, stream>>>(
      qkv, 3072, wPT, 1024, b_proj, (void*)out, 1024, 4, 1024);
}